// Round 10
// baseline (445.943 us; speedup 1.0000x reference)
//
#include <hip/hip_runtime.h>
#include <hip/hip_cooperative_groups.h>

namespace cg = cooperative_groups;

// R10: cooperative mega-kernel, GRID=512 (R9's 1024 sat exactly at the
// co-residency boundary and was rejected; 512 needs only 2 blocks/CU).
// Host checks the coop launch result; on failure falls back to the proven
// R6 4-dispatch path + a DUPLICATED bcast as a timing marker (~246us signal).
//
// out[b,t,u,v] = ye[b,t,v] + yp[b,u,v]
//   ye = enc@W0@W1 (no biases), yp = (pred@W0 + b0)@W1 + b1.

#define BM 64
#define BN 64
#define BK 16
#define LDSS 68     // padded LDS row stride (floats)
#define SPLITK 4
#define MROWS 1280
#define GRID 512    // 2 blocks/CU co-resident — well inside the coop limit

typedef float vf4 __attribute__((ext_vector_type(4)));

__device__ __forceinline__ float4 f4add(float4 a, float4 b) {
    a.x += b.x; a.y += b.y; a.z += b.z; a.w += b.w; return a;
}

// ---------- shared GEMM tile body (used by both paths) ----------
template<int MODE>
__device__ __forceinline__ void gemm_tile(
    const float* __restrict__ A0, const float* __restrict__ A1,
    const float* __restrict__ biasv, const float* __restrict__ Bmat,
    float* __restrict__ C, int N, int K, size_t aStride,
    int row0, int col0, int kbeg, int kend, bool addBias,
    float (&As)[2][BK][LDSS], float (&Bs)[2][BK][LDSS])
{
    __syncthreads();   // previous unit/phase may still be reading LDS

    const int tid = threadIdx.x;
    const int tx = tid & 15;
    const int ty = tid >> 4;
    const int la_row = tid >> 2;
    const int la_k4  = (tid & 3) << 2;
    const int lb_k   = tid >> 4;
    const int lb_n4  = (tid & 15) << 2;

    auto loadA = [&](int k0) -> float4 {
        if (MODE == 0) {
            const float* Ar = (row0 < 1024)
                ? A0 + (size_t)(row0 + la_row) * K
                : A1 + (size_t)(row0 - 1024 + la_row) * K;
            return *reinterpret_cast<const float4*>(Ar + k0 + la_k4);
        } else {
            const size_t o = (size_t)(row0 + la_row) * K + k0 + la_k4;
            float4 a = f4add(*reinterpret_cast<const float4*>(A0 + o),
                             *reinterpret_cast<const float4*>(A0 + aStride + o));
            float4 c = f4add(*reinterpret_cast<const float4*>(A0 + 2 * aStride + o),
                             *reinterpret_cast<const float4*>(A0 + 3 * aStride + o));
            return f4add(a, c);
        }
    };
    auto loadB = [&](int k0) -> float4 {
        return *reinterpret_cast<const float4*>(
            Bmat + (size_t)(k0 + lb_k) * N + col0 + lb_n4);
    };
    auto stage = [&](int buf, float4 av, float4 bv) {
        As[buf][la_k4 + 0][la_row] = av.x;
        As[buf][la_k4 + 1][la_row] = av.y;
        As[buf][la_k4 + 2][la_row] = av.z;
        As[buf][la_k4 + 3][la_row] = av.w;
        *reinterpret_cast<float4*>(&Bs[buf][lb_k][lb_n4]) = bv;
    };

    float acc[4][4] = {};
    auto compute = [&](int buf) {
        #pragma unroll
        for (int kk = 0; kk < BK; ++kk) {
            float4 a = *reinterpret_cast<const float4*>(&As[buf][kk][ty << 2]);
            float4 b = *reinterpret_cast<const float4*>(&Bs[buf][kk][tx << 2]);
            float af[4] = {a.x, a.y, a.z, a.w};
            float bf[4] = {b.x, b.y, b.z, b.w};
            #pragma unroll
            for (int i = 0; i < 4; ++i)
                #pragma unroll
                for (int j = 0; j < 4; ++j)
                    acc[i][j] = fmaf(af[i], bf[j], acc[i][j]);
        }
    };

    stage(0, loadA(kbeg), loadB(kbeg));
    __syncthreads();
    int buf = 0;
    for (int k0 = kbeg + BK; k0 < kend; k0 += BK) {
        float4 av = loadA(k0);
        float4 bv = loadB(k0);
        compute(buf);
        stage(buf ^ 1, av, bv);
        __syncthreads();
        buf ^= 1;
    }
    compute(buf);

    #pragma unroll
    for (int i = 0; i < 4; ++i) {
        const int r = row0 + (ty << 2) + i;
        const int c = col0 + (tx << 2);
        float4 v = make_float4(acc[i][0], acc[i][1], acc[i][2], acc[i][3]);
        if (addBias) {
            v.x += biasv[c]; v.y += biasv[c + 1];
            v.z += biasv[c + 2]; v.w += biasv[c + 3];
        }
        *reinterpret_cast<float4*>(C + (size_t)r * N + c) = v;
    }
}

// ---------- cooperative mega-kernel ----------
__global__ __launch_bounds__(256, 4) void joint_mega(
    const float* __restrict__ pred, const float* __restrict__ enc,
    const float* __restrict__ W0, const float* __restrict__ b0,
    const float* __restrict__ W1, const float* __restrict__ b1,
    float* __restrict__ out,
    float* __restrict__ P, float* __restrict__ Q, float* __restrict__ ypF)
{
    __shared__ float As[2][BK][LDSS];
    __shared__ float Bs[2][BK][LDSS];

    cg::grid_group grid = cg::this_grid();
    const int bid = blockIdx.x;
    const int tid = threadIdx.x;

    // Phase 1: P[z] = [enc;pred]@W0, 8x20 tiles x SK4 = 640 units
    for (int w = bid; w < 8 * 20 * SPLITK; w += GRID) {
        const int z  = w & 3;
        const int t  = w >> 2;
        const int tn = t & 7;
        const int tm = t >> 3;
        gemm_tile<0>(enc, pred, b0, W0, P + (size_t)z * MROWS * 512,
                     512, 512, 0,
                     tm * 64, tn * 64, z * 128, z * 128 + 128,
                     (z == 0) && (tm >= 16), As, Bs);
    }
    grid.sync();

    // Phase 2: Q[z] = (sum_z P)@W1, 16x20 tiles x SK4 = 1280 units
    for (int w = bid; w < 16 * 20 * SPLITK; w += GRID) {
        const int z  = w & 3;
        const int t  = w >> 2;
        const int tn = t & 15;
        const int tm = t >> 4;
        gemm_tile<1>(P, nullptr, b1, W1, Q + (size_t)z * MROWS * 1024,
                     1024, 512, (size_t)MROWS * 512,
                     tm * 64, tn * 64, z * 128, z * 128 + 128,
                     (z == 0) && (tm >= 16), As, Bs);
    }
    grid.sync();

    // Phase 2b: ypF = sum_z Q (pred rows), 65536 float4
    {
        const size_t g = (size_t)bid * 256 + tid;
        if (g < 65536) {
            const float4* Q4 = (const float4*)Q;
            const size_t s = (size_t)MROWS * 256;
            const size_t o = 262144 + g;
            ((float4*)ypF)[g] = f4add(f4add(Q4[o], Q4[o + s]),
                                      f4add(Q4[o + 2 * s], Q4[o + 3 * s]));
        }
    }
    grid.sync();

    // Phase 3: out = ye + yp, 2048 units (bt, uh), NT stores
    const vf4* Qv  = (const vf4*)Q;
    const vf4* ypv = (const vf4*)ypF;
    vf4* ov = (vf4*)out;
    for (int w = bid; w < 2048; w += GRID) {
        const int bt = w >> 1;
        const int uh = w & 1;
        const int v4 = tid;
        const int b = bt >> 9;

        const size_t s = (size_t)MROWS * 256;
        const size_t ybase = ((size_t)bt << 8) + v4;
        vf4 ye = (Qv[ybase] + Qv[ybase + s]) + (Qv[ybase + 2 * s] + Qv[ybase + 3 * s]);

        const vf4* yp = ypv + ((size_t)(b * 128 + uh * 64) << 8) + v4;
        vf4* o = ov + (((size_t)bt * 128 + uh * 64) << 8) + v4;
        #pragma unroll 4
        for (int u = 0; u < 64; ++u) {
            __builtin_nontemporal_store(ye + yp[(size_t)u << 8], o + ((size_t)u << 8));
        }
    }
}

// ---------- fallback path kernels (proven R6) ----------
template<int MODE>
__global__ __launch_bounds__(256) void gemm_sk(
    const float* __restrict__ A0, const float* __restrict__ A1,
    const float* __restrict__ biasv, const float* __restrict__ Bmat,
    float* __restrict__ Cbase, int N, int K, size_t aStride)
{
    __shared__ float As[2][BK][LDSS];
    __shared__ float Bs[2][BK][LDSS];
    const int z = blockIdx.z;
    gemm_tile<MODE>(A0, A1, biasv, Bmat,
                    Cbase + (size_t)z * MROWS * N, N, K, aStride,
                    blockIdx.y * BM, blockIdx.x * BN,
                    z * (K / SPLITK), z * (K / SPLITK) + K / SPLITK,
                    (z == 0) && ((int)blockIdx.y * BM >= 1024),
                    As, Bs);
}

__global__ __launch_bounds__(256) void finalize_yp(
    const float4* __restrict__ Q, float4* __restrict__ ypF)
{
    const int i = blockIdx.x * 256 + threadIdx.x;
    const size_t s = (size_t)MROWS * 256;
    const size_t o = 262144 + (size_t)i;
    ypF[i] = f4add(f4add(Q[o], Q[o + s]), f4add(Q[o + 2 * s], Q[o + 3 * s]));
}

__global__ __launch_bounds__(256) void bcast_add(
    const vf4* __restrict__ Q, const vf4* __restrict__ ypF,
    vf4* __restrict__ out)
{
    const int bid = blockIdx.x;
    const int bt = bid >> 1;
    const int uh = bid & 1;
    const int v4 = threadIdx.x;
    const int b = bt >> 9;

    const size_t s = (size_t)MROWS * 256;
    const size_t ybase = ((size_t)bt << 8) + v4;
    vf4 ye = (Q[ybase] + Q[ybase + s]) + (Q[ybase + 2 * s] + Q[ybase + 3 * s]);

    const vf4* yp = ypF + ((size_t)(b * 128 + uh * 64) << 8) + v4;
    vf4* o = out + (((size_t)bt * 128 + uh * 64) << 8) + v4;
    #pragma unroll 4
    for (int u = 0; u < 64; ++u) {
        __builtin_nontemporal_store(ye + yp[(size_t)u << 8], o + ((size_t)u << 8));
    }
}

extern "C" void kernel_launch(void* const* d_in, const int* in_sizes, int n_in,
                              void* d_out, int out_size, void* d_ws, size_t ws_size,
                              hipStream_t stream)
{
    const float* pred = (const float*)d_in[0];
    const float* enc  = (const float*)d_in[1];
    const float* W0   = (const float*)d_in[2];
    const float* b0   = (const float*)d_in[3];
    const float* W1   = (const float*)d_in[4];
    const float* b1   = (const float*)d_in[5];
    float* out = (float*)d_out;

    float* P   = (float*)d_ws;                       // 4 x [1280][512]
    float* Q   = P + (size_t)SPLITK * MROWS * 512;   // 4 x [1280][1024]
    float* ypF = Q + (size_t)SPLITK * MROWS * 1024;  // [256][1024]

    void* args[] = { (void*)&pred, (void*)&enc, (void*)&W0, (void*)&b0,
                     (void*)&W1, (void*)&b1, (void*)&out,
                     (void*)&P, (void*)&Q, (void*)&ypF };
    hipError_t e = hipLaunchCooperativeKernel((void*)joint_mega, dim3(GRID),
                                              dim3(256), args, 0, stream);
    if (e != hipSuccess) {
        (void)hipGetLastError();   // clear sticky error
        // Proven R6 path + DUPLICATED bcast as timing marker (~246us total
        // signals "cooperative launch rejected" unambiguously).
        gemm_sk<0><<<dim3(512 / BN, MROWS / BM, SPLITK), 256, 0, stream>>>(
            enc, pred, b0, W0, P, 512, 512, 0);
        gemm_sk<1><<<dim3(1024 / BN, MROWS / BM, SPLITK), 256, 0, stream>>>(
            P, nullptr, b1, W1, Q, 1024, 512, (size_t)MROWS * 512);
        finalize_yp<<<256, 256, 0, stream>>>((const float4*)Q, (float4*)ypF);
        bcast_add<<<2048, 256, 0, stream>>>(
            (const vf4*)Q, (const vf4*)ypF, (vf4*)out);
        bcast_add<<<2048, 256, 0, stream>>>(
            (const vf4*)Q, (const vf4*)ypF, (vf4*)out);
    }
}

// Round 11
// 193.893 us; speedup vs baseline: 2.2999x; 2.2999x over previous
//
#include <hip/hip_runtime.h>

// out[b,t,u,v] = ye[b,t,v] + yp[b,u,v]
//   ye = enc@W0@W1 (no biases), yp = (pred@W0 + b0)@W1 + b1.
// R11 (no cooperative launch — R9/R10 showed rejection / 3x regression):
//   D1: P0,P1 = [enc;pred]@W0 split-K=2 partials; b0 on pred rows via z==0.
//   D2: ypF[1024..1279] = (P0+P1)[pred]@W1 + b1   (64 blocks, full K).
//   D3: fused ye-GEMM + broadcast-add:
//       block = 16 bt-rows x 128 v-cols: ye tile in regs (K=512 over P0+P1),
//       yp slice staged in LDS, then 536MB NT store stream (512B segments).

#define BK 16
#define LDSS 68     // padded LDS row stride for 64x64 tiles (floats)
#define SPLITK 2
#define MROWS 1280

typedef float vf4 __attribute__((ext_vector_type(4)));

__device__ __forceinline__ float4 f4add(float4 a, float4 b) {
    a.x += b.x; a.y += b.y; a.z += b.z; a.w += b.w; return a;
}

// 64x64 tile GEMM body. MODE 0: A = [A0(1024 rows); A1] raw.
// MODE 1: A[r][k] = A0[r*K+k] + A0[aStride + r*K+k] (2 split-K partials).
template<int MODE>
__device__ __forceinline__ void gemm_tile(
    const float* __restrict__ A0, const float* __restrict__ A1,
    const float* __restrict__ biasv, const float* __restrict__ Bmat,
    float* __restrict__ C, int N, int K, size_t aStride,
    int row0, int col0, int kbeg, int kend, bool addBias,
    float (&As)[2][BK][LDSS], float (&Bs)[2][BK][LDSS])
{
    const int tid = threadIdx.x;
    const int tx = tid & 15;
    const int ty = tid >> 4;
    const int la_row = tid >> 2;
    const int la_k4  = (tid & 3) << 2;
    const int lb_k   = tid >> 4;
    const int lb_n4  = (tid & 15) << 2;

    auto loadA = [&](int k0) -> float4 {
        if (MODE == 0) {
            const float* Ar = (row0 < 1024)
                ? A0 + (size_t)(row0 + la_row) * K
                : A1 + (size_t)(row0 - 1024 + la_row) * K;
            return *reinterpret_cast<const float4*>(Ar + k0 + la_k4);
        } else {
            const size_t o = (size_t)(row0 + la_row) * K + k0 + la_k4;
            return f4add(*reinterpret_cast<const float4*>(A0 + o),
                         *reinterpret_cast<const float4*>(A0 + aStride + o));
        }
    };
    auto loadB = [&](int k0) -> float4 {
        return *reinterpret_cast<const float4*>(
            Bmat + (size_t)(k0 + lb_k) * N + col0 + lb_n4);
    };
    auto stage = [&](int buf, float4 av, float4 bv) {
        As[buf][la_k4 + 0][la_row] = av.x;
        As[buf][la_k4 + 1][la_row] = av.y;
        As[buf][la_k4 + 2][la_row] = av.z;
        As[buf][la_k4 + 3][la_row] = av.w;
        *reinterpret_cast<float4*>(&Bs[buf][lb_k][lb_n4]) = bv;
    };

    float acc[4][4] = {};
    auto compute = [&](int buf) {
        #pragma unroll
        for (int kk = 0; kk < BK; ++kk) {
            float4 a = *reinterpret_cast<const float4*>(&As[buf][kk][ty << 2]);
            float4 b = *reinterpret_cast<const float4*>(&Bs[buf][kk][tx << 2]);
            float af[4] = {a.x, a.y, a.z, a.w};
            float bf[4] = {b.x, b.y, b.z, b.w};
            #pragma unroll
            for (int i = 0; i < 4; ++i)
                #pragma unroll
                for (int j = 0; j < 4; ++j)
                    acc[i][j] = fmaf(af[i], bf[j], acc[i][j]);
        }
    };

    stage(0, loadA(kbeg), loadB(kbeg));
    __syncthreads();
    int buf = 0;
    for (int k0 = kbeg + BK; k0 < kend; k0 += BK) {
        float4 av = loadA(k0);
        float4 bv = loadB(k0);
        compute(buf);
        stage(buf ^ 1, av, bv);
        __syncthreads();
        buf ^= 1;
    }
    compute(buf);

    #pragma unroll
    for (int i = 0; i < 4; ++i) {
        const int r = row0 + (ty << 2) + i;
        const int c = col0 + (tx << 2);
        float4 v = make_float4(acc[i][0], acc[i][1], acc[i][2], acc[i][3]);
        if (addBias) {
            v.x += biasv[c]; v.y += biasv[c + 1];
            v.z += biasv[c + 2]; v.w += biasv[c + 3];
        }
        *reinterpret_cast<float4*>(C + (size_t)r * N + c) = v;
    }
}

// D1: P[z] = [enc;pred]@W0, z in {0,1}, Kchunk=256; b0 on pred rows via z==0.
__global__ __launch_bounds__(256) void gemm_p(
    const float* __restrict__ enc, const float* __restrict__ pred,
    const float* __restrict__ b0, const float* __restrict__ W0,
    float* __restrict__ P)
{
    __shared__ float As[2][BK][LDSS];
    __shared__ float Bs[2][BK][LDSS];
    const int z = blockIdx.z;
    gemm_tile<0>(enc, pred, b0, W0, P + (size_t)z * MROWS * 512,
                 512, 512, 0,
                 blockIdx.y * 64, blockIdx.x * 64,
                 z * 256, z * 256 + 256,
                 (z == 0) && ((int)blockIdx.y * 64 >= 1024), As, Bs);
}

// D2: ypF rows 1024..1279 = (P0+P1)@W1 + b1, full K. Grid (16, 4).
__global__ __launch_bounds__(256) void gemm_yp(
    const float* __restrict__ P, const float* __restrict__ b1,
    const float* __restrict__ W1, float* __restrict__ ypF)
{
    __shared__ float As[2][BK][LDSS];
    __shared__ float Bs[2][BK][LDSS];
    gemm_tile<1>(P, nullptr, b1, W1, ypF,
                 1024, 512, (size_t)MROWS * 512,
                 1024 + blockIdx.y * 64, blockIdx.x * 64,
                 0, 512, true, As, Bs);
}

// D3: fused ye-GEMM + broadcast-add.
// Block = 16 bt-rows x 128 v-cols. Grid 512 = 64 bt-groups x 8 v-tiles.
// Thread (r8 = tid>>5 in 0..7, c4 = tid&31): owns ye rows {r8, r8+8}, cols c4*4..+3.
__global__ __launch_bounds__(256, 2) void ye_bcast(
    const float* __restrict__ P, const float* __restrict__ W1,
    const float* __restrict__ ypF, float* __restrict__ out)
{
    __shared__ float smem[16384];   // 64KB: GEMM staging first, then yp slice

    const int tid = threadIdx.x;
    const int g   = blockIdx.x >> 3;     // 0..63
    const int vt  = blockIdx.x & 7;      // 0..7
    const int bt0 = g << 4;              // 16 | 512 -> never straddles batch
    const int b   = bt0 >> 9;
    const int r8  = tid >> 5;            // 0..7
    const int c4  = tid & 31;            // 0..31

    float* As = smem;                    // [16][17] = 272 floats
    float* Ws = smem + 272;              // [16][132] = 2112 floats

    const float* A0 = P + (size_t)bt0 * 512;
    const float* A1 = A0 + (size_t)MROWS * 512;
    const float* Wt = W1 + vt * 128;

    vf4 acc0 = {0.f, 0.f, 0.f, 0.f}, acc1 = {0.f, 0.f, 0.f, 0.f};

    for (int k0 = 0; k0 < 512; k0 += 16) {
        __syncthreads();                 // protect prior iter's reads
        if (tid < 64) {
            const int r = tid >> 2, kq = (tid & 3) << 2;
            const float4 a = f4add(
                *reinterpret_cast<const float4*>(A0 + (size_t)r * 512 + k0 + kq),
                *reinterpret_cast<const float4*>(A1 + (size_t)r * 512 + k0 + kq));
            As[(kq + 0) * 17 + r] = a.x;
            As[(kq + 1) * 17 + r] = a.y;
            As[(kq + 2) * 17 + r] = a.z;
            As[(kq + 3) * 17 + r] = a.w;
        }
        {
            const int k = tid >> 4, c16 = (tid & 15) << 2;
            const float* wrow = Wt + (size_t)(k0 + k) * 1024;
            *reinterpret_cast<float4*>(Ws + k * 132 + c16) =
                *reinterpret_cast<const float4*>(wrow + c16);
            *reinterpret_cast<float4*>(Ws + k * 132 + 64 + c16) =
                *reinterpret_cast<const float4*>(wrow + 64 + c16);
        }
        __syncthreads();
        #pragma unroll
        for (int kk = 0; kk < 16; ++kk) {
            const float a0 = As[kk * 17 + r8];
            const float a1 = As[kk * 17 + r8 + 8];
            const vf4 w = *reinterpret_cast<const vf4*>(Ws + kk * 132 + (c4 << 2));
            acc0 += a0 * w;
            acc1 += a1 * w;
        }
    }
    __syncthreads();

    // Stage this block's yp slice: rows b*128..+128 (as ypF rows 1024+), cols vt*128..+128.
    {
        const float4* ys = (const float4*)(ypF + (size_t)(1024 + b * 128) * 1024 + vt * 128);
        float4* yd = (float4*)smem;      // [128][32] float4
        for (int i = tid; i < 4096; i += 256) {
            const int u = i >> 5, cc = i & 31;
            yd[i] = ys[(size_t)u * 256 + cc];
        }
    }
    __syncthreads();

    // Store stream: 2 rows x 128 u per thread; 512B contiguous per 32-lane group.
    const vf4* yps = (const vf4*)smem;
    vf4* o0 = (vf4*)out + (size_t)(bt0 + r8) * 32768 + vt * 32 + c4;
    vf4* o1 = o0 + (size_t)8 * 32768;
    #pragma unroll 4
    for (int u = 0; u < 128; ++u) {
        const vf4 p = yps[(u << 5) + c4];
        __builtin_nontemporal_store(acc0 + p, o0 + (size_t)(u << 8));
        __builtin_nontemporal_store(acc1 + p, o1 + (size_t)(u << 8));
    }
}

extern "C" void kernel_launch(void* const* d_in, const int* in_sizes, int n_in,
                              void* d_out, int out_size, void* d_ws, size_t ws_size,
                              hipStream_t stream)
{
    const float* pred = (const float*)d_in[0];  // [2,128,512]
    const float* enc  = (const float*)d_in[1];  // [2,512,512]
    const float* W0   = (const float*)d_in[2];  // [512,512]
    const float* b0   = (const float*)d_in[3];  // [512]
    const float* W1   = (const float*)d_in[4];  // [512,1024]
    const float* b1   = (const float*)d_in[5];  // [1024]
    float* out = (float*)d_out;                 // [2,512,128,1024] fp32

    float* P   = (float*)d_ws;                       // 2 x [1280][512]
    float* ypF = P + (size_t)SPLITK * MROWS * 512;   // [1280][1024] (rows 1024+ used)

    // D1: P partials (SK2), 320 blocks
    gemm_p<<<dim3(8, 20, SPLITK), 256, 0, stream>>>(enc, pred, b0, W0, P);

    // D2: ypF = (P0+P1)[pred]@W1 + b1, 64 blocks
    gemm_yp<<<dim3(16, 4), 256, 0, stream>>>(P, b1, W1, ypF);

    // D3: fused ye-GEMM + broadcast-add, 512 blocks
    ye_bcast<<<512, 256, 0, stream>>>(P, W1, ypF, out);
}

// Round 12
// 129.602 us; speedup vs baseline: 3.4409x; 1.4961x over previous
//
#include <hip/hip_runtime.h>

// out[b,t,u,v] = ye[b,t,v] + yp[b,u,v]
//   ye = enc@W0@W1 (no biases), yp = (pred@W0 + b0)@W1 + b1.
// R12: bf16-MFMA GEMMs (fp32 accum; inputs rounded to bf16 at LDS staging).
//   D1: P[1280][512] (bf16) = [enc;pred]@W0, +b0 on pred rows.
//   D2: Q[1280][1024] (fp32) = P@W1, +b1 on pred rows.   (finalized, no SK)
//   D3: bcast: out[bt,u,v] = Q[bt,v] + Q[1024+b*128+u, v], NT stores.
// MFMA 16x16x32 bf16; frags: A row=lane&15, k=(lane>>4)*8+j; B col=lane&15,
// same k; C/D col=lane&15, row=(lane>>4)*4+reg (m89-verified mapping).

typedef float vf4 __attribute__((ext_vector_type(4)));
typedef short bf16x8 __attribute__((ext_vector_type(8)));
typedef float f32x4 __attribute__((ext_vector_type(4)));
typedef unsigned short us4 __attribute__((ext_vector_type(4)));

#define PADK 40   // LDS row stride in bf16 (80B: 16B-aligned rows, 2-way banks max)

__device__ __forceinline__ unsigned short f2bf(float f) {
    union { float f; unsigned u; } v; v.f = f;
    const unsigned r = v.u + 0x7FFFu + ((v.u >> 16) & 1u);   // RNE
    return (unsigned short)(r >> 16);
}

// 64x64 tile, 4 waves, BK=32, single-buffer LDS with register prefetch.
// A_BF16: A is bf16 [.][K] (P). else fp32 rows from [A0(1024 rows); A1].
// C_BF16: C stored bf16, else fp32. bias added when row0>=1024.
template<bool A_BF16, bool C_BF16>
__global__ __launch_bounds__(256) void gemm_mfma(
    const void* __restrict__ Aptr, const float* __restrict__ A1,
    const float* __restrict__ Bmat,     // fp32 [K][N] row-major
    const float* __restrict__ biasv,
    void* __restrict__ Cptr, int N, int K)
{
    __shared__ unsigned short As[64 * PADK];    // [row][k]
    __shared__ unsigned short Bst[64 * PADK];   // transposed: [n][k]

    const int tid  = threadIdx.x;
    const int row0 = blockIdx.y * 64;
    const int col0 = blockIdx.x * 64;
    const int w    = tid >> 6;
    const int lane = tid & 63;
    const int l16  = lane & 15;
    const int kq   = lane >> 4;          // 0..3

    float4 ar[2]; bf16x8 ab; float4 br[2];

    auto loadA = [&](int kb) {
        if (A_BF16) {
            const unsigned short* A = (const unsigned short*)Aptr;
            const int r = tid >> 2, k8 = (tid & 3) << 3;
            ab = *reinterpret_cast<const bf16x8*>(A + (size_t)(row0 + r) * K + kb + k8);
        } else {
            #pragma unroll
            for (int i = 0; i < 2; ++i) {
                const int idx = tid + (i << 8);
                const int r = idx >> 3, k4 = (idx & 7) << 2;
                const float* Arow = (row0 < 1024)
                    ? (const float*)Aptr + (size_t)(row0 + r) * K
                    : A1 + (size_t)(row0 - 1024 + r) * K;
                ar[i] = *reinterpret_cast<const float4*>(Arow + kb + k4);
            }
        }
    };
    auto loadB = [&](int kb) {
        #pragma unroll
        for (int i = 0; i < 2; ++i) {
            const int idx = tid + (i << 8);
            const int kk = idx >> 4, n4 = (idx & 15) << 2;
            br[i] = *reinterpret_cast<const float4*>(Bmat + (size_t)(kb + kk) * N + col0 + n4);
        }
    };
    auto stage = [&]() {
        if (A_BF16) {
            const int r = tid >> 2, k8 = (tid & 3) << 3;
            *reinterpret_cast<bf16x8*>(&As[r * PADK + k8]) = ab;
        } else {
            #pragma unroll
            for (int i = 0; i < 2; ++i) {
                const int idx = tid + (i << 8);
                const int r = idx >> 3, k4 = (idx & 7) << 2;
                us4 p = { f2bf(ar[i].x), f2bf(ar[i].y), f2bf(ar[i].z), f2bf(ar[i].w) };
                *reinterpret_cast<us4*>(&As[r * PADK + k4]) = p;
            }
        }
        #pragma unroll
        for (int i = 0; i < 2; ++i) {
            const int idx = tid + (i << 8);
            const int kk = idx >> 4, n4 = (idx & 15) << 2;
            Bst[(n4 + 0) * PADK + kk] = f2bf(br[i].x);
            Bst[(n4 + 1) * PADK + kk] = f2bf(br[i].y);
            Bst[(n4 + 2) * PADK + kk] = f2bf(br[i].z);
            Bst[(n4 + 3) * PADK + kk] = f2bf(br[i].w);
        }
    };

    f32x4 acc[4] = {};
    const unsigned short* a_base = &As[(w * 16 + l16) * PADK + kq * 8];

    loadA(0); loadB(0);
    const int nkt = K >> 5;
    for (int kt = 0; kt < nkt; ++kt) {
        __syncthreads();                 // prior compute done reading LDS
        stage();
        __syncthreads();
        if (kt + 1 < nkt) { loadA((kt + 1) << 5); loadB((kt + 1) << 5); }
        bf16x8 a = *reinterpret_cast<const bf16x8*>(a_base);
        #pragma unroll
        for (int nf = 0; nf < 4; ++nf) {
            bf16x8 b = *reinterpret_cast<const bf16x8*>(&Bst[(nf * 16 + l16) * PADK + kq * 8]);
            acc[nf] = __builtin_amdgcn_mfma_f32_16x16x32_bf16(a, b, acc[nf], 0, 0, 0);
        }
    }

    const int cr0 = row0 + w * 16 + kq * 4;
    const bool doBias = (row0 >= 1024);
    #pragma unroll
    for (int nf = 0; nf < 4; ++nf) {
        const int c = col0 + nf * 16 + l16;
        const float bv = doBias ? biasv[c] : 0.0f;
        #pragma unroll
        for (int r = 0; r < 4; ++r) {
            const float v = acc[nf][r] + bv;
            if (C_BF16) ((unsigned short*)Cptr)[(size_t)(cr0 + r) * N + c] = f2bf(v);
            else        ((float*)Cptr)[(size_t)(cr0 + r) * N + c] = v;
        }
    }
}

// out[(bt*128+u)*256+v4] = Q[bt*256+v4] + Q[(1024+b*128+u)*256+v4]
// grid 2048: bt = bid>>1, uh = bid&1; 256 threads = v4. NT stores. (R6-proven.)
__global__ __launch_bounds__(256) void bcast_add(
    const vf4* __restrict__ Q, vf4* __restrict__ out)
{
    const int bid = blockIdx.x;
    const int bt = bid >> 1;
    const int uh = bid & 1;
    const int v4 = threadIdx.x;
    const int b = bt >> 9;

    const vf4 ye = Q[((size_t)bt << 8) + v4];
    const vf4* yp = Q + ((size_t)(1024 + b * 128 + uh * 64) << 8) + v4;
    vf4* o = out + (((size_t)bt * 128 + uh * 64) << 8) + v4;
    #pragma unroll 4
    for (int u = 0; u < 64; ++u) {
        __builtin_nontemporal_store(ye + yp[(size_t)u << 8], o + ((size_t)u << 8));
    }
}

extern "C" void kernel_launch(void* const* d_in, const int* in_sizes, int n_in,
                              void* d_out, int out_size, void* d_ws, size_t ws_size,
                              hipStream_t stream)
{
    const float* pred = (const float*)d_in[0];  // [2,128,512]
    const float* enc  = (const float*)d_in[1];  // [2,512,512]
    const float* W0   = (const float*)d_in[2];  // [512,512]
    const float* b0   = (const float*)d_in[3];  // [512]
    const float* W1   = (const float*)d_in[4];  // [512,1024]
    const float* b1   = (const float*)d_in[5];  // [1024]
    float* out = (float*)d_out;                 // [2,512,128,1024] fp32

    char* base = (char*)d_ws;
    unsigned short* P = (unsigned short*)base;          // bf16 [1280][512] = 1.31MB
    float* Q = (float*)(base + (size_t)(1 << 21));      // fp32 [1280][1024] = 5.24MB

    // D1: P = [enc;pred]@W0 (+b0 on pred rows), bf16 out. 8x20 = 160 blocks.
    gemm_mfma<false, true><<<dim3(8, 20), 256, 0, stream>>>(
        enc, pred, W0, b0, P, 512, 512);

    // D2: Q = P@W1 (+b1 on pred rows), fp32 out. 16x20 = 320 blocks.
    gemm_mfma<true, false><<<dim3(16, 20), 256, 0, stream>>>(
        P, nullptr, W1, b1, Q, 1024, 512);

    // D3: out = ye + yp (536 MB NT write)
    bcast_add<<<2048, 256, 0, stream>>>((const vf4*)Q, (vf4*)out);
}

// Round 13
// 121.273 us; speedup vs baseline: 3.6772x; 1.0687x over previous
//
#include <hip/hip_runtime.h>

// out[b,t,u,v] = ye[b,t,v] + yp[b,u,v]
//   ye = enc@W0@W1 (no biases), yp = (pred@W0 + b0)@W1 + b1.
// R13: D1/D2 identical to R12 (bf16-MFMA GEMMs). bcast restructured to a
// register outer-product: 16 coalesced L2 loads/thread up front (8 ye + 8 yp
// vf4), then a pure 64x NT-store stream (no loads interleaved).
//   D1: P[1280][512] (bf16) = [enc;pred]@W0, +b0 on pred rows.
//   D2: Q[1280][1024] (fp32) = P@W1, +b1 on pred rows.
//   D3: bcast: block = 8bt x 64u x 128v; grid 2048.

typedef float vf4 __attribute__((ext_vector_type(4)));
typedef short bf16x8 __attribute__((ext_vector_type(8)));
typedef float f32x4 __attribute__((ext_vector_type(4)));
typedef unsigned short us4 __attribute__((ext_vector_type(4)));

#define PADK 40   // LDS row stride in bf16 (80B: 16B-aligned rows, 2-way banks max)

__device__ __forceinline__ unsigned short f2bf(float f) {
    union { float f; unsigned u; } v; v.f = f;
    const unsigned r = v.u + 0x7FFFu + ((v.u >> 16) & 1u);   // RNE
    return (unsigned short)(r >> 16);
}

// 64x64 tile, 4 waves, BK=32, single-buffer LDS with register prefetch.
// A_BF16: A is bf16 [.][K] (P). else fp32 rows from [A0(1024 rows); A1].
// C_BF16: C stored bf16, else fp32. bias added when row0>=1024.
template<bool A_BF16, bool C_BF16>
__global__ __launch_bounds__(256) void gemm_mfma(
    const void* __restrict__ Aptr, const float* __restrict__ A1,
    const float* __restrict__ Bmat,     // fp32 [K][N] row-major
    const float* __restrict__ biasv,
    void* __restrict__ Cptr, int N, int K)
{
    __shared__ unsigned short As[64 * PADK];    // [row][k]
    __shared__ unsigned short Bst[64 * PADK];   // transposed: [n][k]

    const int tid  = threadIdx.x;
    const int row0 = blockIdx.y * 64;
    const int col0 = blockIdx.x * 64;
    const int w    = tid >> 6;
    const int lane = tid & 63;
    const int l16  = lane & 15;
    const int kq   = lane >> 4;          // 0..3

    float4 ar[2]; bf16x8 ab; float4 br[2];

    auto loadA = [&](int kb) {
        if (A_BF16) {
            const unsigned short* A = (const unsigned short*)Aptr;
            const int r = tid >> 2, k8 = (tid & 3) << 3;
            ab = *reinterpret_cast<const bf16x8*>(A + (size_t)(row0 + r) * K + kb + k8);
        } else {
            #pragma unroll
            for (int i = 0; i < 2; ++i) {
                const int idx = tid + (i << 8);
                const int r = idx >> 3, k4 = (idx & 7) << 2;
                const float* Arow = (row0 < 1024)
                    ? (const float*)Aptr + (size_t)(row0 + r) * K
                    : A1 + (size_t)(row0 - 1024 + r) * K;
                ar[i] = *reinterpret_cast<const float4*>(Arow + kb + k4);
            }
        }
    };
    auto loadB = [&](int kb) {
        #pragma unroll
        for (int i = 0; i < 2; ++i) {
            const int idx = tid + (i << 8);
            const int kk = idx >> 4, n4 = (idx & 15) << 2;
            br[i] = *reinterpret_cast<const float4*>(Bmat + (size_t)(kb + kk) * N + col0 + n4);
        }
    };
    auto stage = [&]() {
        if (A_BF16) {
            const int r = tid >> 2, k8 = (tid & 3) << 3;
            *reinterpret_cast<bf16x8*>(&As[r * PADK + k8]) = ab;
        } else {
            #pragma unroll
            for (int i = 0; i < 2; ++i) {
                const int idx = tid + (i << 8);
                const int r = idx >> 3, k4 = (idx & 7) << 2;
                us4 p = { f2bf(ar[i].x), f2bf(ar[i].y), f2bf(ar[i].z), f2bf(ar[i].w) };
                *reinterpret_cast<us4*>(&As[r * PADK + k4]) = p;
            }
        }
        #pragma unroll
        for (int i = 0; i < 2; ++i) {
            const int idx = tid + (i << 8);
            const int kk = idx >> 4, n4 = (idx & 15) << 2;
            Bst[(n4 + 0) * PADK + kk] = f2bf(br[i].x);
            Bst[(n4 + 1) * PADK + kk] = f2bf(br[i].y);
            Bst[(n4 + 2) * PADK + kk] = f2bf(br[i].z);
            Bst[(n4 + 3) * PADK + kk] = f2bf(br[i].w);
        }
    };

    f32x4 acc[4] = {};
    const unsigned short* a_base = &As[(w * 16 + l16) * PADK + kq * 8];

    loadA(0); loadB(0);
    const int nkt = K >> 5;
    for (int kt = 0; kt < nkt; ++kt) {
        __syncthreads();                 // prior compute done reading LDS
        stage();
        __syncthreads();
        if (kt + 1 < nkt) { loadA((kt + 1) << 5); loadB((kt + 1) << 5); }
        bf16x8 a = *reinterpret_cast<const bf16x8*>(a_base);
        #pragma unroll
        for (int nf = 0; nf < 4; ++nf) {
            bf16x8 b = *reinterpret_cast<const bf16x8*>(&Bst[(nf * 16 + l16) * PADK + kq * 8]);
            acc[nf] = __builtin_amdgcn_mfma_f32_16x16x32_bf16(a, b, acc[nf], 0, 0, 0);
        }
    }

    const int cr0 = row0 + w * 16 + kq * 4;
    const bool doBias = (row0 >= 1024);
    #pragma unroll
    for (int nf = 0; nf < 4; ++nf) {
        const int c = col0 + nf * 16 + l16;
        const float bv = doBias ? biasv[c] : 0.0f;
        #pragma unroll
        for (int r = 0; r < 4; ++r) {
            const float v = acc[nf][r] + bv;
            if (C_BF16) ((unsigned short*)Cptr)[(size_t)(cr0 + r) * N + c] = f2bf(v);
            else        ((float*)Cptr)[(size_t)(cr0 + r) * N + c] = v;
        }
    }
}

// D3: register outer-product bcast. Grid 2048 = 128 bt-groups x 2 uh x 8 vt.
// Thread (u8 = tid>>5, c4 = tid&31): preloads ye[8] (bt rows) and yp[8]
// (u rows) vf4 into registers — all coalesced 512B segments from L2 — then
// issues 64 pure NT stores (8 bt x 8 u), no loads in the stream.
__global__ __launch_bounds__(256) void bcast_add(
    const vf4* __restrict__ Q, vf4* __restrict__ out)
{
    const int bid = blockIdx.x;
    const int g   = bid >> 4;            // 0..127
    const int uh  = (bid >> 3) & 1;      // 0..1
    const int vt  = bid & 7;             // 0..7
    const int bt0 = g << 3;              // 8 | 512 -> never straddles batch
    const int b   = bt0 >> 9;
    const int u8  = threadIdx.x >> 5;    // 0..7
    const int c4  = threadIdx.x & 31;    // 0..31
    const int vcol = vt * 32 + c4;       // 0..255 (vf4 col)

    vf4 ye[8], yp[8];
    #pragma unroll
    for (int i = 0; i < 8; ++i)
        ye[i] = Q[(size_t)(bt0 + i) * 256 + vcol];
    const int urow0 = 1024 + b * 128 + uh * 64 + u8 * 8;
    #pragma unroll
    for (int i = 0; i < 8; ++i)
        yp[i] = Q[(size_t)(urow0 + i) * 256 + vcol];

    #pragma unroll
    for (int bt = 0; bt < 8; ++bt) {
        vf4* o = out + ((size_t)(bt0 + bt) * 128 + uh * 64 + u8 * 8) * 256 + vcol;
        #pragma unroll
        for (int uu = 0; uu < 8; ++uu) {
            __builtin_nontemporal_store(ye[bt] + yp[uu], o + (size_t)uu * 256);
        }
    }
}

extern "C" void kernel_launch(void* const* d_in, const int* in_sizes, int n_in,
                              void* d_out, int out_size, void* d_ws, size_t ws_size,
                              hipStream_t stream)
{
    const float* pred = (const float*)d_in[0];  // [2,128,512]
    const float* enc  = (const float*)d_in[1];  // [2,512,512]
    const float* W0   = (const float*)d_in[2];  // [512,512]
    const float* b0   = (const float*)d_in[3];  // [512]
    const float* W1   = (const float*)d_in[4];  // [512,1024]
    const float* b1   = (const float*)d_in[5];  // [1024]
    float* out = (float*)d_out;                 // [2,512,128,1024] fp32

    char* base = (char*)d_ws;
    unsigned short* P = (unsigned short*)base;          // bf16 [1280][512] = 1.31MB
    float* Q = (float*)(base + (size_t)(1 << 21));      // fp32 [1280][1024] = 5.24MB

    // D1: P = [enc;pred]@W0 (+b0 on pred rows), bf16 out. 8x20 = 160 blocks.
    gemm_mfma<false, true><<<dim3(8, 20), 256, 0, stream>>>(
        enc, pred, W0, b0, P, 512, 512);

    // D2: Q = P@W1 (+b1 on pred rows), fp32 out. 16x20 = 320 blocks.
    gemm_mfma<true, false><<<dim3(16, 20), 256, 0, stream>>>(
        P, nullptr, W1, b1, Q, 1024, 512);

    // D3: out = ye + yp (536 MB NT write, load-free store stream)
    bcast_add<<<2048, 256, 0, stream>>>((const vf4*)Q, (vf4*)out);
}